// Round 1
// baseline (269.173 us; speedup 1.0000x reference)
//
#include <hip/hip_runtime.h>
#include <math.h>

#define BGRAPHS 256
#define NNODES  1024
#define CCH     64
#define NEDGE   4194304
#define KKEEP   512

typedef unsigned long long u64;
typedef unsigned int u32;

// Output layout (flat float32 elements)
#define OFF_XP   0
#define OFF_EI0  8388608
#define OFF_EI1  (8388608 + NEDGE)
#define OFF_EA   16777216
#define OFF_BP   20971520
#define OFF_SC   21102592
#define OFF_PM   21364736
#define OFF_MSK  21495808

// One block (1024 threads) per graph: scores + bitonic top-k + perm/batch/new_idx + x_p gather.
__global__ __launch_bounds__(1024) void topk_kernel(
    const float* __restrict__ x, const float* __restrict__ w,
    const float* __restrict__ bias, const int* __restrict__ batch,
    float* __restrict__ xp, float* __restrict__ bpo, float* __restrict__ sco,
    float* __restrict__ pmo, int* __restrict__ new_idx)
{
    __shared__ float s_w[CCH];
    __shared__ u64 s_key[NNODES];

    const int b = blockIdx.x;
    const int tid = threadIdx.x;

    if (tid < CCH) s_w[tid] = w[tid];
    __syncthreads();

    // ||w|| in fp64 (monotone scale, exact value only matters for the scores output, 4% tol)
    double n2 = 0.0;
    #pragma unroll
    for (int k = 0; k < CCH; ++k) { double v = (double)s_w[k]; n2 += v * v; }
    const float nrm = (float)sqrt(n2);
    const float bv = bias[0];

    // dot(x_row, w) with fp64 accumulation (nearest to exact -> minimizes rank flips vs np fp32)
    const float4* x4 = (const float4*)x;
    const int node = b * NNODES + tid;
    double acc = 0.0;
    #pragma unroll
    for (int k = 0; k < 16; ++k) {
        float4 xv = x4[node * 16 + k];
        acc += (double)xv.x * (double)s_w[4 * k + 0];
        acc += (double)xv.y * (double)s_w[4 * k + 1];
        acc += (double)xv.z * (double)s_w[4 * k + 2];
        acc += (double)xv.w * (double)s_w[4 * k + 3];
    }
    const float score = ((float)acc + bv) / nrm;
    sco[node] = score;

    // key: descending score (primary), ascending index (secondary) -> sort u64 ascending
    u32 u = __float_as_uint(score);
    u32 mu = u ^ (u32)(((int)u >> 31) | 0x80000000);  // ascending monotone map
    u32 hi = ~mu;                                      // descending
    s_key[tid] = ((u64)hi << 32) | (u32)tid;

    // bitonic sort (ascending), 1024 elements, 1 thread/element
    for (int k = 2; k <= NNODES; k <<= 1) {
        for (int j = k >> 1; j > 0; j >>= 1) {
            __syncthreads();
            int ixj = tid ^ j;
            if (ixj > tid) {
                u64 a = s_key[tid], c = s_key[ixj];
                bool up = ((tid & k) == 0);
                if ((a > c) == up) { s_key[tid] = c; s_key[ixj] = a; }
            }
        }
    }
    __syncthreads();

    // perm / batch_p / new_idx
    const int lidx = (int)(u32)s_key[tid];
    if (tid < KKEEP) {
        const int g = b * NNODES + lidx;
        pmo[b * KKEEP + tid] = (float)g;
        bpo[b * KKEEP + tid] = (float)batch[g];
        new_idx[g] = b * KKEEP + tid;
    } else {
        new_idx[b * NNODES + lidx] = -1;
    }

    // gather x_p: 512 rows x 16 float4 = 8192 float4s, 8 per thread, coalesced writes
    float4* xp4 = (float4*)xp;
    #pragma unroll
    for (int p = 0; p < 8; ++p) {
        int elem = tid + p * 1024;        // < 8192
        int row = elem >> 4, col = elem & 15;
        int src = (int)(u32)s_key[row];   // sorted local index, rows 0..511
        xp4[(b * KKEEP + row) * 16 + col] = x4[(b * NNODES + src) * 16 + col];
    }
}

// 4 edges per thread, vectorized loads/stores; new_idx gathers hit L2 (1 MiB table).
__global__ __launch_bounds__(256) void edge_kernel(
    const int* __restrict__ ei, const float* __restrict__ ea,
    const int* __restrict__ new_idx,
    float* __restrict__ ei0o, float* __restrict__ ei1o,
    float* __restrict__ eao, float* __restrict__ msk)
{
    const int gid = blockIdx.x * 256 + threadIdx.x;   // one per 4 edges
    const int4* s4p = (const int4*)ei;
    const int4* d4p = (const int4*)(ei + NEDGE);
    const float4* a4p = (const float4*)ea;

    int4 s4 = s4p[gid];
    int4 d4 = d4p[gid];
    float4 a4 = a4p[gid];
    float4 r4, c4, o4, m4;

#define PROC(comp)                                            \
    {                                                         \
        int r = new_idx[s4.comp];                             \
        int c = new_idx[d4.comp];                             \
        int m = (r >= 0) && (c >= 0);                         \
        r4.comp = m ? (float)r : -1.0f;                       \
        c4.comp = m ? (float)c : -1.0f;                       \
        o4.comp = m ? a4.comp : 0.0f;                         \
        m4.comp = (float)m;                                   \
    }
    PROC(x) PROC(y) PROC(z) PROC(w)
#undef PROC

    ((float4*)ei0o)[gid] = r4;
    ((float4*)ei1o)[gid] = c4;
    ((float4*)eao)[gid]  = o4;
    ((float4*)msk)[gid]  = m4;
}

extern "C" void kernel_launch(void* const* d_in, const int* in_sizes, int n_in,
                              void* d_out, int out_size, void* d_ws, size_t ws_size,
                              hipStream_t stream) {
    const float* x          = (const float*)d_in[0];
    const float* w          = (const float*)d_in[1];
    const float* bias       = (const float*)d_in[2];
    const int*   edge_index = (const int*)d_in[3];
    const float* edge_attr  = (const float*)d_in[4];
    const int*   batch      = (const int*)d_in[5];

    float* out = (float*)d_out;
    float* xp   = out + OFF_XP;
    float* ei0o = out + OFF_EI0;
    float* ei1o = out + OFF_EI1;
    float* eao  = out + OFF_EA;
    float* bpo  = out + OFF_BP;
    float* sco  = out + OFF_SC;
    float* pmo  = out + OFF_PM;
    float* msk  = out + OFF_MSK;

    int* new_idx = (int*)d_ws;   // B*N ints = 1 MiB, fully rewritten every call

    topk_kernel<<<BGRAPHS, 1024, 0, stream>>>(x, w, bias, batch, xp, bpo, sco, pmo, new_idx);
    edge_kernel<<<NEDGE / 4 / 256, 256, 0, stream>>>(edge_index, edge_attr, new_idx,
                                                     ei0o, ei1o, eao, msk);
}

// Round 3
// 251.619 us; speedup vs baseline: 1.0698x; 1.0698x over previous
//
#include <hip/hip_runtime.h>
#include <math.h>

#define BGRAPHS 256
#define NNODES  1024
#define CCH     64
#define NEDGE   4194304
#define KKEEP   512

typedef unsigned long long u64;
typedef unsigned int u32;
typedef unsigned short u16;
typedef float  f32x4 __attribute__((ext_vector_type(4)));
typedef int    i32x4 __attribute__((ext_vector_type(4)));

// Output layout (flat float32 elements)
#define OFF_XP   0
#define OFF_EI0  8388608
#define OFF_EI1  (8388608 + NEDGE)
#define OFF_EA   16777216
#define OFF_BP   20971520
#define OFF_SC   21102592
#define OFF_PM   21364736
#define OFF_MSK  21495808

// ---------------- Kernel A: scores (streaming, full occupancy) ----------------
__global__ __launch_bounds__(256) void score_kernel(
    const float* __restrict__ x, const float* __restrict__ w,
    const float* __restrict__ bias, float* __restrict__ sco)
{
    __shared__ float s_w[CCH];
    const int tid = threadIdx.x;
    if (tid < CCH) s_w[tid] = w[tid];
    __syncthreads();

    // ||w|| in fp64 (monotone; exact value only matters for the scores output)
    double n2 = 0.0;
    #pragma unroll
    for (int k = 0; k < CCH; ++k) { double v = (double)s_w[k]; n2 += v * v; }
    const float nrm = (float)sqrt(n2);
    const float bv = bias[0];

    const int node = blockIdx.x * 256 + tid;
    const f32x4* x4 = (const f32x4*)x;
    double acc = 0.0;
    #pragma unroll
    for (int k = 0; k < 16; ++k) {
        f32x4 xv = x4[node * 16 + k];
        acc += (double)xv.x * (double)s_w[4 * k + 0];
        acc += (double)xv.y * (double)s_w[4 * k + 1];
        acc += (double)xv.z * (double)s_w[4 * k + 2];
        acc += (double)xv.w * (double)s_w[4 * k + 3];
    }
    sco[node] = ((float)acc + bv) / nrm;
}

// ---------------- Kernel B: per-graph bitonic top-k ----------------
__global__ __launch_bounds__(1024) void sort_kernel(
    const float* __restrict__ sco, const int* __restrict__ batch,
    float* __restrict__ pmo, float* __restrict__ bpo,
    u16* __restrict__ table16, u16* __restrict__ src16)
{
    __shared__ u64 s_key[NNODES];
    const int b = blockIdx.x;
    const int tid = threadIdx.x;
    const int node = b * NNODES + tid;

    const float score = sco[node];
    // key: descending score (primary), ascending index (secondary) -> ascending u64 sort
    u32 u = __float_as_uint(score);
    u32 mu = u ^ (u32)(((int)u >> 31) | 0x80000000);
    s_key[tid] = ((u64)(~mu) << 32) | (u32)tid;

    for (int k = 2; k <= NNODES; k <<= 1) {
        for (int j = k >> 1; j > 0; j >>= 1) {
            __syncthreads();
            int ixj = tid ^ j;
            if (ixj > tid) {
                u64 a = s_key[tid], c = s_key[ixj];
                bool up = ((tid & k) == 0);
                if ((a > c) == up) { s_key[tid] = c; s_key[ixj] = a; }
            }
        }
    }
    __syncthreads();

    const int lidx = (int)(u32)s_key[tid];
    const int g = b * NNODES + lidx;
    if (tid < KKEEP) {
        pmo[b * KKEEP + tid] = (float)g;
        bpo[b * KKEEP + tid] = (float)batch[g];
        table16[g] = (u16)tid;               // local rank 0..511
        src16[b * KKEEP + tid] = (u16)lidx;  // source local node for gather
    } else {
        table16[g] = 0xFFFFu;
    }
}

// ---------------- Kernel C: x_p gather ----------------
__global__ __launch_bounds__(256) void gather_kernel(
    const float* __restrict__ x, const u16* __restrict__ src16,
    float* __restrict__ xp)
{
    const int elem = blockIdx.x * 256 + threadIdx.x;  // < B*K*16
    const int row = elem >> 4;                        // kept-row id 0..B*K-1
    const int col = elem & 15;
    const int b = row >> 9;                           // /KKEEP
    const int src = (int)src16[row];
    const f32x4* x4 = (const f32x4*)x;
    ((f32x4*)xp)[elem] = x4[((b << 10) + src) * 16 + col];
}

// ---------------- Kernel D: edge filter (u16 table, nontemporal streams) ----------------
__global__ __launch_bounds__(256) void edge_kernel(
    const int* __restrict__ ei, const float* __restrict__ ea,
    const u16* __restrict__ table16,
    float* __restrict__ ei0o, float* __restrict__ ei1o,
    float* __restrict__ eao, float* __restrict__ msk)
{
    const int gid = blockIdx.x * 256 + threadIdx.x;   // one per 4 edges
    const i32x4* s4p = (const i32x4*)ei;
    const i32x4* d4p = (const i32x4*)(ei + NEDGE);
    const f32x4* a4p = (const f32x4*)ea;

    i32x4 s4 = __builtin_nontemporal_load(&s4p[gid]);
    i32x4 d4 = __builtin_nontemporal_load(&d4p[gid]);
    f32x4 a4 = __builtin_nontemporal_load(&a4p[gid]);
    f32x4 r4, c4, o4, m4;

#define PROC(comp)                                                 \
    {                                                              \
        u16 vs = table16[s4.comp];                                 \
        u16 vd = table16[d4.comp];                                 \
        int m = (vs != 0xFFFFu) && (vd != 0xFFFFu);                \
        int r = ((s4.comp >> 10) << 9) + (int)vs;                  \
        int c = ((d4.comp >> 10) << 9) + (int)vd;                  \
        r4.comp = m ? (float)r : -1.0f;                            \
        c4.comp = m ? (float)c : -1.0f;                            \
        o4.comp = m ? a4.comp : 0.0f;                              \
        m4.comp = (float)m;                                        \
    }
    PROC(x) PROC(y) PROC(z) PROC(w)
#undef PROC

    __builtin_nontemporal_store(r4, &((f32x4*)ei0o)[gid]);
    __builtin_nontemporal_store(c4, &((f32x4*)ei1o)[gid]);
    __builtin_nontemporal_store(o4, &((f32x4*)eao)[gid]);
    __builtin_nontemporal_store(m4, &((f32x4*)msk)[gid]);
}

extern "C" void kernel_launch(void* const* d_in, const int* in_sizes, int n_in,
                              void* d_out, int out_size, void* d_ws, size_t ws_size,
                              hipStream_t stream) {
    const float* x          = (const float*)d_in[0];
    const float* w          = (const float*)d_in[1];
    const float* bias       = (const float*)d_in[2];
    const int*   edge_index = (const int*)d_in[3];
    const float* edge_attr  = (const float*)d_in[4];
    const int*   batch      = (const int*)d_in[5];

    float* out = (float*)d_out;
    float* xp   = out + OFF_XP;
    float* ei0o = out + OFF_EI0;
    float* ei1o = out + OFF_EI1;
    float* eao  = out + OFF_EA;
    float* bpo  = out + OFF_BP;
    float* sco  = out + OFF_SC;
    float* pmo  = out + OFF_PM;
    float* msk  = out + OFF_MSK;

    u16* table16 = (u16*)d_ws;                          // B*N u16 = 512 KiB
    u16* src16   = (u16*)d_ws + BGRAPHS * NNODES;       // B*K u16 = 256 KiB

    score_kernel<<<BGRAPHS * NNODES / 256, 256, 0, stream>>>(x, w, bias, sco);
    sort_kernel<<<BGRAPHS, 1024, 0, stream>>>(sco, batch, pmo, bpo, table16, src16);
    gather_kernel<<<BGRAPHS * KKEEP * 16 / 256, 256, 0, stream>>>(x, src16, xp);
    edge_kernel<<<NEDGE / 4 / 256, 256, 0, stream>>>(edge_index, edge_attr, table16,
                                                     ei0o, ei1o, eao, msk);
}

// Round 4
// 244.823 us; speedup vs baseline: 1.0995x; 1.0278x over previous
//
#include <hip/hip_runtime.h>
#include <math.h>

#define BGRAPHS 256
#define NNODES  1024
#define CCH     64
#define NEDGE   4194304
#define KKEEP   512

typedef unsigned long long u64;
typedef unsigned int u32;
typedef unsigned short u16;
typedef float  f32x4 __attribute__((ext_vector_type(4)));
typedef int    i32x4 __attribute__((ext_vector_type(4)));

// Output layout (flat float32 elements)
#define OFF_XP   0
#define OFF_EI0  8388608
#define OFF_EI1  (8388608 + NEDGE)
#define OFF_EA   16777216
#define OFF_BP   20971520
#define OFF_SC   21102592
#define OFF_PM   21364736
#define OFF_MSK  21495808

// fused-kernel grid split
#define EDGE_BLOCKS   2048   // E/8/256 threads, 8 edges per thread
#define GATHER_BLOCKS 8192   // B*K*16 float4 / 256

// ---------------- Kernel A: scores (streaming, full occupancy) ----------------
__global__ __launch_bounds__(256) void score_kernel(
    const float* __restrict__ x, const float* __restrict__ w,
    const float* __restrict__ bias, float* __restrict__ sco)
{
    __shared__ float s_w[CCH];
    const int tid = threadIdx.x;
    if (tid < CCH) s_w[tid] = w[tid];
    __syncthreads();

    double n2 = 0.0;
    #pragma unroll
    for (int k = 0; k < CCH; ++k) { double v = (double)s_w[k]; n2 += v * v; }
    const float nrm = (float)sqrt(n2);
    const float bv = bias[0];

    const int node = blockIdx.x * 256 + tid;
    const f32x4* x4 = (const f32x4*)x;
    double acc = 0.0;
    #pragma unroll
    for (int k = 0; k < 16; ++k) {
        f32x4 xv = x4[node * 16 + k];
        acc += (double)xv.x * (double)s_w[4 * k + 0];
        acc += (double)xv.y * (double)s_w[4 * k + 1];
        acc += (double)xv.z * (double)s_w[4 * k + 2];
        acc += (double)xv.w * (double)s_w[4 * k + 3];
    }
    sco[node] = ((float)acc + bv) / nrm;
}

// ---------------- Kernel B: per-graph bitonic top-k (wave-level inner phases) -------
__device__ __forceinline__ u64 cmpex(u64 key, int j, bool dir, int tid) {
    u64 o = (u64)__shfl_xor((long long)key, j, 64);
    bool lower = ((tid & j) == 0);
    u64 mn = key < o ? key : o;
    u64 mx = key < o ? o : key;
    return (dir == lower) ? mn : mx;
}

__global__ __launch_bounds__(1024) void sort_kernel(
    const float* __restrict__ sco, const int* __restrict__ batch,
    float* __restrict__ pmo, float* __restrict__ bpo,
    u16* __restrict__ table16, u16* __restrict__ src16)
{
    __shared__ u64 s_key[NNODES];
    const int b = blockIdx.x;
    const int tid = threadIdx.x;
    const int node = b * NNODES + tid;

    const float score = sco[node];
    // key: descending score (primary), ascending index (secondary) -> ascending u64 sort
    u32 u = __float_as_uint(score);
    u32 mu = u ^ (u32)(((int)u >> 31) | 0x80000000);
    u64 key = ((u64)(~mu) << 32) | (u32)tid;

    // k = 2..64: fully intra-wave (partner = lane ^ j, j <= 32)
    #pragma unroll
    for (int k = 2; k <= 64; k <<= 1) {
        bool dir = ((tid & k) == 0);
        for (int j = k >> 1; j > 0; j >>= 1)
            key = cmpex(key, j, dir, tid);
    }
    s_key[tid] = key;

    // k = 128..1024: LDS steps for j >= 64, then intra-wave tail
    for (int k = 128; k <= NNODES; k <<= 1) {
        bool dir = ((tid & k) == 0);
        for (int j = k >> 1; j >= 64; j >>= 1) {
            __syncthreads();
            int ixj = tid ^ j;
            if (ixj > tid) {
                u64 a = s_key[tid], c = s_key[ixj];
                if ((a > c) == dir) { s_key[tid] = c; s_key[ixj] = a; }
            }
        }
        __syncthreads();
        key = s_key[tid];
        #pragma unroll
        for (int j = 32; j > 0; j >>= 1)
            key = cmpex(key, j, dir, tid);
        s_key[tid] = key;
    }
    // key now = sorted element at position tid (no barrier needed: we read our own slot)

    const int lidx = (int)(u32)key;
    const int g = b * NNODES + lidx;
    if (tid < KKEEP) {
        pmo[b * KKEEP + tid] = (float)g;
        bpo[b * KKEEP + tid] = (float)batch[g];
        table16[g] = (u16)tid;               // local rank 0..511
        src16[b * KKEEP + tid] = (u16)lidx;  // source local node for gather
    } else {
        table16[g] = 0xFFFFu;
    }
}

// ---------------- Kernel C: fused edge-filter + x_p gather ----------------
// Edge blocks first (long pole), gather blocks fill in behind.
__global__ __launch_bounds__(256) void edge_gather_kernel(
    const int* __restrict__ ei, const float* __restrict__ ea,
    const u16* __restrict__ table16,
    const float* __restrict__ x, const u16* __restrict__ src16,
    float* __restrict__ ei0o, float* __restrict__ ei1o,
    float* __restrict__ eao, float* __restrict__ msk,
    float* __restrict__ xp)
{
    const int tid = threadIdx.x;
    if (blockIdx.x < EDGE_BLOCKS) {
        // ---- edge path: 8 edges/thread, 2 fully-coalesced int4 slots ----
        const int i0 = blockIdx.x * 512 + tid;   // int4 index (4 edges)
        const int i1 = i0 + 256;
        const i32x4* s4p = (const i32x4*)ei;
        const i32x4* d4p = (const i32x4*)(ei + NEDGE);
        const f32x4* a4p = (const f32x4*)ea;

        i32x4 sA = __builtin_nontemporal_load(&s4p[i0]);
        i32x4 sB = __builtin_nontemporal_load(&s4p[i1]);
        i32x4 dA = __builtin_nontemporal_load(&d4p[i0]);
        i32x4 dB = __builtin_nontemporal_load(&d4p[i1]);
        f32x4 aA = __builtin_nontemporal_load(&a4p[i0]);
        f32x4 aB = __builtin_nontemporal_load(&a4p[i1]);

        // issue all 16 table gathers before any use (max MLP)
        u16 vsA[4], vdA[4], vsB[4], vdB[4];
        #pragma unroll
        for (int q = 0; q < 4; ++q) vsA[q] = table16[((const int*)&sA)[q]];
        #pragma unroll
        for (int q = 0; q < 4; ++q) vdA[q] = table16[((const int*)&dA)[q]];
        #pragma unroll
        for (int q = 0; q < 4; ++q) vsB[q] = table16[((const int*)&sB)[q]];
        #pragma unroll
        for (int q = 0; q < 4; ++q) vdB[q] = table16[((const int*)&dB)[q]];

        f32x4 rA, cA, oA, mA, rB, cB, oB, mB;
        #pragma unroll
        for (int q = 0; q < 4; ++q) {
            {
                int m = (vsA[q] != 0xFFFFu) && (vdA[q] != 0xFFFFu);
                int r = ((((const int*)&sA)[q] >> 10) << 9) + (int)vsA[q];
                int c = ((((const int*)&dA)[q] >> 10) << 9) + (int)vdA[q];
                ((float*)&rA)[q] = m ? (float)r : -1.0f;
                ((float*)&cA)[q] = m ? (float)c : -1.0f;
                ((float*)&oA)[q] = m ? ((const float*)&aA)[q] : 0.0f;
                ((float*)&mA)[q] = (float)m;
            }
            {
                int m = (vsB[q] != 0xFFFFu) && (vdB[q] != 0xFFFFu);
                int r = ((((const int*)&sB)[q] >> 10) << 9) + (int)vsB[q];
                int c = ((((const int*)&dB)[q] >> 10) << 9) + (int)vdB[q];
                ((float*)&rB)[q] = m ? (float)r : -1.0f;
                ((float*)&cB)[q] = m ? (float)c : -1.0f;
                ((float*)&oB)[q] = m ? ((const float*)&aB)[q] : 0.0f;
                ((float*)&mB)[q] = (float)m;
            }
        }

        __builtin_nontemporal_store(rA, &((f32x4*)ei0o)[i0]);
        __builtin_nontemporal_store(rB, &((f32x4*)ei0o)[i1]);
        __builtin_nontemporal_store(cA, &((f32x4*)ei1o)[i0]);
        __builtin_nontemporal_store(cB, &((f32x4*)ei1o)[i1]);
        __builtin_nontemporal_store(oA, &((f32x4*)eao)[i0]);
        __builtin_nontemporal_store(oB, &((f32x4*)eao)[i1]);
        __builtin_nontemporal_store(mA, &((f32x4*)msk)[i0]);
        __builtin_nontemporal_store(mB, &((f32x4*)msk)[i1]);
    } else {
        // ---- gather path: one float4 of x_p per thread ----
        const int elem = (blockIdx.x - EDGE_BLOCKS) * 256 + tid;  // < B*K*16
        const int row = elem >> 4;
        const int col = elem & 15;
        const int b = row >> 9;
        const int src = (int)src16[row];
        const f32x4* x4 = (const f32x4*)x;
        ((f32x4*)xp)[elem] = x4[((b << 10) + src) * 16 + col];
    }
}

extern "C" void kernel_launch(void* const* d_in, const int* in_sizes, int n_in,
                              void* d_out, int out_size, void* d_ws, size_t ws_size,
                              hipStream_t stream) {
    const float* x          = (const float*)d_in[0];
    const float* w          = (const float*)d_in[1];
    const float* bias       = (const float*)d_in[2];
    const int*   edge_index = (const int*)d_in[3];
    const float* edge_attr  = (const float*)d_in[4];
    const int*   batch      = (const int*)d_in[5];

    float* out = (float*)d_out;
    float* xp   = out + OFF_XP;
    float* ei0o = out + OFF_EI0;
    float* ei1o = out + OFF_EI1;
    float* eao  = out + OFF_EA;
    float* bpo  = out + OFF_BP;
    float* sco  = out + OFF_SC;
    float* pmo  = out + OFF_PM;
    float* msk  = out + OFF_MSK;

    u16* table16 = (u16*)d_ws;                          // B*N u16 = 512 KiB
    u16* src16   = (u16*)d_ws + BGRAPHS * NNODES;       // B*K u16 = 256 KiB

    score_kernel<<<BGRAPHS * NNODES / 256, 256, 0, stream>>>(x, w, bias, sco);
    sort_kernel<<<BGRAPHS, 1024, 0, stream>>>(sco, batch, pmo, bpo, table16, src16);
    edge_gather_kernel<<<EDGE_BLOCKS + GATHER_BLOCKS, 256, 0, stream>>>(
        edge_index, edge_attr, table16, x, src16, ei0o, ei1o, eao, msk, xp);
}

// Round 5
// 237.806 us; speedup vs baseline: 1.1319x; 1.0295x over previous
//
#include <hip/hip_runtime.h>
#include <math.h>

#define BGRAPHS 256
#define NNODES  1024
#define CCH     64
#define NEDGE   4194304
#define KKEEP   512

typedef unsigned long long u64;
typedef unsigned int u32;
typedef unsigned short u16;
typedef float  f32x4 __attribute__((ext_vector_type(4)));
typedef int    i32x4 __attribute__((ext_vector_type(4)));

// Output layout (flat float32 elements)
#define OFF_XP   0
#define OFF_EI0  8388608
#define OFF_EI1  (8388608 + NEDGE)
#define OFF_EA   16777216
#define OFF_BP   20971520
#define OFF_SC   21102592
#define OFF_PM   21364736
#define OFF_MSK  21495808

#define FUSED_BLOCKS 2048       // 524288 threads: 8 edges + 4 xp-float4s each
#define GTHREADS     524288

// ---------------- Kernel A: scores (streaming, full occupancy) ----------------
__global__ __launch_bounds__(256) void score_kernel(
    const float* __restrict__ x, const float* __restrict__ w,
    const float* __restrict__ bias, float* __restrict__ sco)
{
    __shared__ float s_w[CCH];
    const int tid = threadIdx.x;
    if (tid < CCH) s_w[tid] = w[tid];
    __syncthreads();

    double n2 = 0.0;
    #pragma unroll
    for (int k = 0; k < CCH; ++k) { double v = (double)s_w[k]; n2 += v * v; }
    const float nrm = (float)sqrt(n2);
    const float bv = bias[0];

    const int node = blockIdx.x * 256 + tid;
    const f32x4* x4 = (const f32x4*)x;
    double acc = 0.0;
    #pragma unroll
    for (int k = 0; k < 16; ++k) {
        f32x4 xv = x4[node * 16 + k];
        acc += (double)xv.x * (double)s_w[4 * k + 0];
        acc += (double)xv.y * (double)s_w[4 * k + 1];
        acc += (double)xv.z * (double)s_w[4 * k + 2];
        acc += (double)xv.w * (double)s_w[4 * k + 3];
    }
    sco[node] = ((float)acc + bv) / nrm;
}

// ---------------- Kernel B: per-graph bitonic top-k (wave-level inner phases) -------
__device__ __forceinline__ u64 cmpex(u64 key, int j, bool dir, int tid) {
    u64 o = (u64)__shfl_xor((long long)key, j, 64);
    bool lower = ((tid & j) == 0);
    u64 mn = key < o ? key : o;
    u64 mx = key < o ? o : key;
    return (dir == lower) ? mn : mx;
}

__global__ __launch_bounds__(1024) void sort_kernel(
    const float* __restrict__ sco, const int* __restrict__ batch,
    float* __restrict__ pmo, float* __restrict__ bpo,
    u16* __restrict__ table16, u16* __restrict__ src16)
{
    __shared__ u64 s_key[NNODES];
    const int b = blockIdx.x;
    const int tid = threadIdx.x;
    const int node = b * NNODES + tid;

    const float score = sco[node];
    // key: descending score (primary), ascending index (secondary) -> ascending u64 sort
    u32 u = __float_as_uint(score);
    u32 mu = u ^ (u32)(((int)u >> 31) | 0x80000000);
    u64 key = ((u64)(~mu) << 32) | (u32)tid;

    // k = 2..64: fully intra-wave (partner = lane ^ j, j <= 32)
    #pragma unroll
    for (int k = 2; k <= 64; k <<= 1) {
        bool dir = ((tid & k) == 0);
        for (int j = k >> 1; j > 0; j >>= 1)
            key = cmpex(key, j, dir, tid);
    }
    s_key[tid] = key;

    // k = 128..1024: LDS steps for j >= 64, then intra-wave tail
    for (int k = 128; k <= NNODES; k <<= 1) {
        bool dir = ((tid & k) == 0);
        for (int j = k >> 1; j >= 64; j >>= 1) {
            __syncthreads();
            int ixj = tid ^ j;
            if (ixj > tid) {
                u64 a = s_key[tid], c = s_key[ixj];
                if ((a > c) == dir) { s_key[tid] = c; s_key[ixj] = a; }
            }
        }
        __syncthreads();
        key = s_key[tid];
        #pragma unroll
        for (int j = 32; j > 0; j >>= 1)
            key = cmpex(key, j, dir, tid);
        s_key[tid] = key;
    }

    const int lidx = (int)(u32)key;
    const int g = b * NNODES + lidx;
    if (tid < KKEEP) {
        pmo[b * KKEEP + tid] = (float)g;
        bpo[b * KKEEP + tid] = (float)batch[g];
        table16[g] = (u16)tid;               // local rank 0..511
        src16[b * KKEEP + tid] = (u16)lidx;  // source local node for gather
    } else {
        table16[g] = 0xFFFFu;
    }
}

// ---------------- Kernel C: uniform fused edge-filter + x_p gather ----------------
// Every thread: 8 edges (16 table gathers) + 4 float4 of x_p. The x_p streaming
// work fills latency slots while table gathers (L2-bound) are in flight.
__global__ __launch_bounds__(256) void edge_gather_kernel(
    const int* __restrict__ ei, const float* __restrict__ ea,
    const u16* __restrict__ table16,
    const float* __restrict__ x, const u16* __restrict__ src16,
    float* __restrict__ ei0o, float* __restrict__ ei1o,
    float* __restrict__ eao, float* __restrict__ msk,
    float* __restrict__ xp)
{
    const int tid = threadIdx.x;
    const int gt = blockIdx.x * 256 + tid;      // 0..GTHREADS-1
    const int i0 = blockIdx.x * 512 + tid;      // int4 slot A (4 edges)
    const int i1 = i0 + 256;                    // int4 slot B

    const i32x4* s4p = (const i32x4*)ei;
    const i32x4* d4p = (const i32x4*)(ei + NEDGE);
    const f32x4* a4p = (const f32x4*)ea;
    const f32x4* x4  = (const f32x4*)x;

    // --- round 1: independent loads (6 edge streams + 4 src16) ---
    i32x4 sA = __builtin_nontemporal_load(&s4p[i0]);
    i32x4 sB = __builtin_nontemporal_load(&s4p[i1]);
    i32x4 dA = __builtin_nontemporal_load(&d4p[i0]);
    i32x4 dB = __builtin_nontemporal_load(&d4p[i1]);
    f32x4 aA = __builtin_nontemporal_load(&a4p[i0]);
    f32x4 aB = __builtin_nontemporal_load(&a4p[i1]);

    int rowv[4], colv[4], srcv[4];
    #pragma unroll
    for (int p = 0; p < 4; ++p) {
        int elem = gt + p * GTHREADS;
        rowv[p] = elem >> 4;
        colv[p] = elem & 15;
        srcv[p] = (int)src16[rowv[p]];    // 16 lanes share a row -> near-broadcast
    }

    // --- round 2: the 16 scattered table gathers (the critical resource) ---
    u16 vsA[4], vdA[4], vsB[4], vdB[4];
    #pragma unroll
    for (int q = 0; q < 4; ++q) vsA[q] = table16[((const int*)&sA)[q]];
    #pragma unroll
    for (int q = 0; q < 4; ++q) vdA[q] = table16[((const int*)&dA)[q]];
    #pragma unroll
    for (int q = 0; q < 4; ++q) vsB[q] = table16[((const int*)&sB)[q]];
    #pragma unroll
    for (int q = 0; q < 4; ++q) vdB[q] = table16[((const int*)&dB)[q]];

    // --- round 3: x_p source rows (overlap table-gather drain) ---
    f32x4 xv[4];
    #pragma unroll
    for (int p = 0; p < 4; ++p) {
        int b = rowv[p] >> 9;
        xv[p] = x4[((b << 10) + srcv[p]) * 16 + colv[p]];
    }

    // --- compute + stores (edge outputs) ---
    f32x4 rA, cA, oA, mA, rB, cB, oB, mB;
    #pragma unroll
    for (int q = 0; q < 4; ++q) {
        {
            int m = (vsA[q] != 0xFFFFu) && (vdA[q] != 0xFFFFu);
            int r = ((((const int*)&sA)[q] >> 10) << 9) + (int)vsA[q];
            int c = ((((const int*)&dA)[q] >> 10) << 9) + (int)vdA[q];
            ((float*)&rA)[q] = m ? (float)r : -1.0f;
            ((float*)&cA)[q] = m ? (float)c : -1.0f;
            ((float*)&oA)[q] = m ? ((const float*)&aA)[q] : 0.0f;
            ((float*)&mA)[q] = (float)m;
        }
        {
            int m = (vsB[q] != 0xFFFFu) && (vdB[q] != 0xFFFFu);
            int r = ((((const int*)&sB)[q] >> 10) << 9) + (int)vsB[q];
            int c = ((((const int*)&dB)[q] >> 10) << 9) + (int)vdB[q];
            ((float*)&rB)[q] = m ? (float)r : -1.0f;
            ((float*)&cB)[q] = m ? (float)c : -1.0f;
            ((float*)&oB)[q] = m ? ((const float*)&aB)[q] : 0.0f;
            ((float*)&mB)[q] = (float)m;
        }
    }

    __builtin_nontemporal_store(rA, &((f32x4*)ei0o)[i0]);
    __builtin_nontemporal_store(rB, &((f32x4*)ei0o)[i1]);
    __builtin_nontemporal_store(cA, &((f32x4*)ei1o)[i0]);
    __builtin_nontemporal_store(cB, &((f32x4*)ei1o)[i1]);
    __builtin_nontemporal_store(oA, &((f32x4*)eao)[i0]);
    __builtin_nontemporal_store(oB, &((f32x4*)eao)[i1]);
    __builtin_nontemporal_store(mA, &((f32x4*)msk)[i0]);
    __builtin_nontemporal_store(mB, &((f32x4*)msk)[i1]);

    // --- x_p stores ---
    #pragma unroll
    for (int p = 0; p < 4; ++p)
        __builtin_nontemporal_store(xv[p], &((f32x4*)xp)[gt + p * GTHREADS]);
}

extern "C" void kernel_launch(void* const* d_in, const int* in_sizes, int n_in,
                              void* d_out, int out_size, void* d_ws, size_t ws_size,
                              hipStream_t stream) {
    const float* x          = (const float*)d_in[0];
    const float* w          = (const float*)d_in[1];
    const float* bias       = (const float*)d_in[2];
    const int*   edge_index = (const int*)d_in[3];
    const float* edge_attr  = (const float*)d_in[4];
    const int*   batch      = (const int*)d_in[5];

    float* out = (float*)d_out;
    float* xp   = out + OFF_XP;
    float* ei0o = out + OFF_EI0;
    float* ei1o = out + OFF_EI1;
    float* eao  = out + OFF_EA;
    float* bpo  = out + OFF_BP;
    float* sco  = out + OFF_SC;
    float* pmo  = out + OFF_PM;
    float* msk  = out + OFF_MSK;

    u16* table16 = (u16*)d_ws;                          // B*N u16 = 512 KiB
    u16* src16   = (u16*)d_ws + BGRAPHS * NNODES;       // B*K u16 = 256 KiB

    score_kernel<<<BGRAPHS * NNODES / 256, 256, 0, stream>>>(x, w, bias, sco);
    sort_kernel<<<BGRAPHS, 1024, 0, stream>>>(sco, batch, pmo, bpo, table16, src16);
    edge_gather_kernel<<<FUSED_BLOCKS, 256, 0, stream>>>(
        edge_index, edge_attr, table16, x, src16, ei0o, ei1o, eao, msk, xp);
}